// Round 5
// baseline (388.306 us; speedup 1.0000x reference)
//
#include <hip/hip_runtime.h>
#include <math.h>

#define Bsz 64
#define Tn 1000
#define QD 1024
#define MD 512
#define AD 128
#define NF 32
#define KS 31
#define PADc 15

#define NCH 16     // t-chunks
#define RPC 64     // rows per chunk
#define SUB 16     // rows per MFMA subtile
#define ROWSH 520  // shorts per LDS row (512 data + 8 pad) = 1040 B

typedef __attribute__((ext_vector_type(8))) short bf16x8;
typedef __attribute__((ext_vector_type(4))) float f32x4;

// d_ws layout (bytes)
#define OFF_ENERG 32768
#define OFF_WMF  288768
#define OFF_W2F  419840
#define OFF_ML   428032
#define OFF_CTXC 436224
#define OFF_CNT  2533376   // 64 x u32 tail counters (zeroed by k_prep each iter)

static __device__ __forceinline__ short f2bf(float x) {
    unsigned u = __float_as_uint(x);
    unsigned r = (u + 0x7fffu + ((u >> 16) & 1u)) >> 16;  // RNE
    return (short)r;
}
static __device__ __forceinline__ float bf2f(short s) {
    return __uint_as_float(((unsigned)(unsigned short)s) << 16);
}
static __device__ __forceinline__ float fast_tanh(float x) {
    float e2 = __expf(2.f * x);
    return 1.f - 2.f / (e2 + 1.f);
}

// ---------------------------------------------------------------------------
// Kernel A (prep, 97 blocks x 256): WmF fragment-major bf16; qsum; W2F;
// zero the tail counters (workspace is poisoned each iteration).
// ---------------------------------------------------------------------------
__global__ __launch_bounds__(256)
void k_prep(const float* __restrict__ Wm, const float* __restrict__ conv_w,
            const float* __restrict__ conv_b, const float* __restrict__ Wloc,
            const float* __restrict__ query, const float* __restrict__ Wq,
            const float* __restrict__ bq, const float* __restrict__ bm,
            short* __restrict__ WmF, short* __restrict__ W2F,
            float* __restrict__ qsum, unsigned* __restrict__ cnt) {
    __shared__ float qs[QD];
    __shared__ float red[256];
    int bid = blockIdx.x;
    if (bid < 32) {
        int g = bid * 256 + threadIdx.x;
        int wc = g >> 6, l = g & 63;
        int a = (wc >> 4) * 16 + (l & 15);
        int kb = (wc & 15) * 32 + (l >> 4) * 8;
        const float* src = Wm + a * MD + kb;
        float4 v0 = *(const float4*)src;
        float4 v1 = *(const float4*)(src + 4);
        bf16x8 o;
        o[0] = f2bf(v0.x); o[1] = f2bf(v0.y); o[2] = f2bf(v0.z); o[3] = f2bf(v0.w);
        o[4] = f2bf(v1.x); o[5] = f2bf(v1.y); o[6] = f2bf(v1.z); o[7] = f2bf(v1.w);
        *(bf16x8*)(WmF + (size_t)g * 8) = o;
    } else if (bid < 96) {
        int b = bid - 32;
        int a = threadIdx.x & 127;
        int half_ = threadIdx.x >> 7;
        for (int i = threadIdx.x; i < QD; i += 256) qs[i] = query[b * QD + i];
        __syncthreads();
        const float4* Wq4 = (const float4*)(Wq + a * QD + half_ * (QD / 2));
        const float4* qs4 = (const float4*)(qs + half_ * (QD / 2));
        float acc = 0.f;
#pragma unroll 4
        for (int i = 0; i < QD / 8; ++i) {
            float4 w = Wq4[i];
            float4 q = qs4[i];
            acc += w.x * q.x + w.y * q.y + w.z * q.z + w.w * q.w;
        }
        red[threadIdx.x] = acc;
        __syncthreads();
        if (half_ == 0) {
            float b2 = 0.f;
            for (int f = 0; f < NF; ++f) b2 += conv_b[f] * Wloc[a * NF + f];
            qsum[b * AD + a] = red[a] + red[a + 128] + bq[a] + bm[a] + b2;
        }
    } else {
        if (threadIdx.x < Bsz) cnt[threadIdx.x] = 0u;  // tail counters
        for (int s = threadIdx.x * 2; s < threadIdx.x * 2 + 2; ++s) {
            int w = s >> 6, l = s & 63;
            int a = w * 16 + (l & 15);
            int kb = (l >> 4) * 8;
            bf16x8 o;
#pragma unroll
            for (int j = 0; j < 8; ++j) {
                int k = kb + j;
                float sum = 0.f;
                if (k < KS)
                    for (int f = 0; f < NF; ++f) sum += conv_w[f * KS + k] * Wloc[a * NF + f];
                o[j] = f2bf(sum);  // k>=KS columns are ZERO -> no A-side guard needed
            }
            *(bf16x8*)(W2F + s * 8) = o;
        }
    }
}

// ---------------------------------------------------------------------------
// Kernel B: fused energies + softmax + context + TAIL-COMBINE.
//   R4 structure (depth-2 reg staging, 8 waves, 66.5 KB chunk) unchanged.
//   New: after the epilogue stores, each block releases (syncthreads ->
//   threadfence -> atomicAdd cnt[b]); the 16th block for batch b acquires
//   and runs the combine (old k_combine body) for b, overlapped with other
//   batches' main-loop work. Saves the 64-block mostly-idle launch + gap.
// ---------------------------------------------------------------------------
__global__ __launch_bounds__(512, 4)
void k_fused(const float* __restrict__ mem, const float* __restrict__ awc,
             const unsigned char* __restrict__ mask,
             const short* __restrict__ WmF, const short* __restrict__ W2F,
             const float* __restrict__ Wv, const float* __restrict__ bv,
             const float* __restrict__ qsum, float* __restrict__ energ,
             float* __restrict__ ctxc, float2* __restrict__ ml,
             unsigned* __restrict__ cnt, float* __restrict__ ctx,
             float* __restrict__ wout) {
    __shared__ __align__(16) short chunk[RPC * ROWSH];  // 66560 B
    __shared__ float ered[8][SUB + 1];
    __shared__ float Esub[RPC];
    __shared__ float ps[RPC];
    __shared__ float vmask[RPC];
    __shared__ short awcsB[96];
    __shared__ float smc[NCH], slc[NCH];
    __shared__ int sflag;

    const int b = blockIdx.y, c = blockIdx.x;
    const int t0 = c * RPC;
    const int tid = threadIdx.x;
    const int w = tid >> 6, lane = tid & 63, m16 = lane & 15, q = lane >> 4;

    // --- prologue: issue subtile 0 AND subtile 1 loads (depth-2 prime) ---
    const float* gbase = mem + (size_t)b * Tn * MD + lane * 8;
    float4 stg[2][2][2];
#pragma unroll
    for (int s = 0; s < 2; ++s) {
#pragma unroll
        for (int rr = 0; rr < 2; ++rr) {
            int t = t0 + s * SUB + w * 2 + rr;
            int tc = t < Tn ? t : Tn - 1;
            const float* gp = gbase + (size_t)tc * MD;
            stg[s][rr][0] = *(const float4*)gp;
            stg[s][rr][1] = *(const float4*)(gp + 4);
        }
    }

    // --- stage awc window [t0-15, t0+79] and row-validity into LDS ---
    if (tid < 96) {
        int g = t0 - PADc + tid;
        float v = (tid <= 94 && g >= 0 && g < Tn) ? awc[b * Tn + g] : 0.f;
        awcsB[tid] = f2bf(v);
    }
    if (tid < RPC) {
        int t = t0 + tid;
        bool valid = (t < Tn) && (mask[b * Tn + (t < Tn ? t : 0)] == 0);
        vmask[tid] = valid ? 1.f : 0.f;
    }

    // --- B fragments ---
    bf16x8 bfr[17];
#pragma unroll
    for (int cc = 0; cc < 16; ++cc) bfr[cc] = ((const bf16x8*)WmF)[(w * 16 + cc) * 64 + lane];
    bfr[16] = ((const bf16x8*)W2F)[w * 64 + lane];

    const int a = w * 16 + m16;
    const float wvv = Wv[a];
    const float qsv = qsum[b * AD + a];
    const float bv0 = bv[0];

    asm volatile("s_waitcnt lgkmcnt(0)" ::: "memory");
    __builtin_amdgcn_s_barrier();  // awcsB / vmask visible

#pragma unroll
    for (int s = 0; s < 4; ++s) {
        const int pb = s & 1;
        // consume subtile-s registers (compiler inserts exact vmcnt wait)
#pragma unroll
        for (int rr = 0; rr < 2; ++rr) {
            int row = s * SUB + w * 2 + rr;
            float4 v0 = stg[pb][rr][0];
            float4 v1 = stg[pb][rr][1];
            bf16x8 o;
            o[0] = f2bf(v0.x); o[1] = f2bf(v0.y); o[2] = f2bf(v0.z); o[3] = f2bf(v0.w);
            o[4] = f2bf(v1.x); o[5] = f2bf(v1.y); o[6] = f2bf(v1.z); o[7] = f2bf(v1.w);
            *(bf16x8*)(&chunk[row * ROWSH] + lane * 8) = o;
        }
        // THEN issue subtile-(s+2) loads into the just-freed slot.
        if (s < 2) {
#pragma unroll
            for (int rr = 0; rr < 2; ++rr) {
                int t = t0 + (s + 2) * SUB + w * 2 + rr;
                int tc = t < Tn ? t : Tn - 1;
                const float* gp = gbase + (size_t)tc * MD;
                stg[pb][rr][0] = *(const float4*)gp;
                stg[pb][rr][1] = *(const float4*)(gp + 4);
            }
        }
        asm volatile("s_waitcnt lgkmcnt(0)" ::: "memory");  // ds_writes done
        __builtin_amdgcn_s_barrier();                       // subtile s visible

        f32x4 acc = (f32x4){0.f, 0.f, 0.f, 0.f};
        const short* arow = &chunk[(s * SUB + m16) * ROWSH + q * 8];
#pragma unroll
        for (int cc = 0; cc < 16; ++cc) {
            bf16x8 af = *(const bf16x8*)(arow + cc * 32);
            acc = __builtin_amdgcn_mfma_f32_16x16x32_bf16(af, bfr[cc], acc, 0, 0, 0);
        }
        {   // location chunk: Toeplitz window from LDS (k=31 col zeroed in W2F)
            int tl = s * SUB + m16;
            bf16x8 af;
#pragma unroll
            for (int j = 0; j < 8; ++j) af[j] = awcsB[tl + q * 8 + j];
            acc = __builtin_amdgcn_mfma_f32_16x16x32_bf16(af, bfr[16], acc, 0, 0, 0);
        }

        // per-row energy partials: tanh, dot Wv, reduce over 16 a-lanes
#pragma unroll
        for (int r = 0; r < 4; ++r) {
            float e = wvv * fast_tanh(acc[r] + qsv);
#pragma unroll
            for (int m2 = 1; m2 < 16; m2 <<= 1) e += __shfl_xor(e, m2, 64);
            if (m16 == 0) ered[w][q * 4 + r] = e;
        }
        asm volatile("s_waitcnt lgkmcnt(0)" ::: "memory");
        __builtin_amdgcn_s_barrier();
        if (tid < SUB) {
            float E = bv0;
#pragma unroll
            for (int ww = 0; ww < 8; ++ww) E += ered[ww][tid];
            Esub[s * SUB + tid] = E;
        }
        // ered reuse in s+1 is safe: next write happens after s+1's top barrier
    }

    asm volatile("s_waitcnt lgkmcnt(0)" ::: "memory");
    __builtin_amdgcn_s_barrier();  // Esub complete

    // --- block softmax over the 64 resident rows ---
    float mx = -1e30f;
#pragma unroll
    for (int r = 0; r < RPC; ++r) {
        float e = (vmask[r] != 0.f) ? Esub[r] : -1e30f;
        mx = fmaxf(mx, e);
    }
    if (tid < RPC) ps[tid] = vmask[tid] * __expf(Esub[tid] - mx);
    asm volatile("s_waitcnt lgkmcnt(0)" ::: "memory");
    __builtin_amdgcn_s_barrier();

    // --- context: thread j accumulates m-dim j from the LDS chunk ---
    float ctxj = 0.f, psum = 0.f;
#pragma unroll 8
    for (int r = 0; r < RPC; ++r) {
        float p = ps[r];
        psum += p;
        ctxj += p * bf2f(chunk[r * ROWSH + tid]);
    }
    ctxc[((size_t)c * Bsz + b) * MD + tid] = ctxj;
    if (tid < RPC) {
        int t = t0 + tid;
        if (t < Tn) energ[b * Tn + t] = Esub[tid];
    }
    if (tid == 0) ml[c * Bsz + b] = make_float2(mx, psum);

    // --- tail-combine: 16th finisher for batch b runs the combine ---
    __syncthreads();  // all this block's global stores drained (vmcnt in wait)
    if (tid == 0) {
        __threadfence();                        // release: make stores visible
        unsigned old = atomicAdd(&cnt[b], 1u);  // device-scope
        sflag = (old == NCH - 1) ? 1 : 0;
    }
    __syncthreads();
    if (sflag) {
        __threadfence();  // acquire: see other blocks' ctxc/ml/energ
        if (tid < NCH) {
            float2 v = ml[tid * Bsz + b];
            smc[tid] = v.x;
            slc[tid] = v.y;
        }
        __syncthreads();
        float M = -1e30f;
#pragma unroll
        for (int cc = 0; cc < NCH; ++cc) M = fmaxf(M, smc[cc]);
        float L = 0.f;
#pragma unroll
        for (int cc = 0; cc < NCH; ++cc) L += slc[cc] * __expf(smc[cc] - M);
        float inv = 1.f / L;

        float sacc = 0.f;
#pragma unroll
        for (int cc = 0; cc < NCH; ++cc)
            sacc += ctxc[((size_t)cc * Bsz + b) * MD + tid] * __expf(smc[cc] - M);
        ctx[b * MD + tid] = sacc * inv;

#pragma unroll
        for (int i = 0; i < 2; ++i) {
            int t = tid + i * 512;
            if (t < Tn) {
                bool msk = mask[b * Tn + t] != 0;
                float e = energ[b * Tn + t];
                wout[b * Tn + t] = msk ? 0.f : __expf(e - M) * inv;
            }
        }
    }
}

// ---------------------------------------------------------------------------
extern "C" void kernel_launch(void* const* d_in, const int* in_sizes, int n_in,
                              void* d_out, int out_size, void* d_ws, size_t ws_size,
                              hipStream_t stream) {
    const float* query  = (const float*)d_in[0];
    const float* memory = (const float*)d_in[1];
    const float* awc    = (const float*)d_in[2];
    const unsigned char* mask = (const unsigned char*)d_in[3];
    const float* Wq     = (const float*)d_in[4];
    const float* bq     = (const float*)d_in[5];
    const float* Wm     = (const float*)d_in[6];
    const float* bm     = (const float*)d_in[7];
    const float* Wv     = (const float*)d_in[8];
    const float* bv     = (const float*)d_in[9];
    const float* conv_w = (const float*)d_in[10];
    const float* conv_b = (const float*)d_in[11];
    const float* Wloc   = (const float*)d_in[12];

    float* out = (float*)d_out;
    float* ctx = out;             // [64,512]
    float* wout = out + Bsz * MD; // [64,1000]

    float* qsum  = (float*)d_ws;
    float* energ = (float*)((char*)d_ws + OFF_ENERG);
    short* WmF   = (short*)((char*)d_ws + OFF_WMF);
    short* W2F   = (short*)((char*)d_ws + OFF_W2F);
    float2* ml   = (float2*)((char*)d_ws + OFF_ML);
    float* ctxc  = (float*)((char*)d_ws + OFF_CTXC);
    unsigned* cnt = (unsigned*)((char*)d_ws + OFF_CNT);

    k_prep<<<dim3(97), dim3(256), 0, stream>>>(Wm, conv_w, conv_b, Wloc, query, Wq,
                                               bq, bm, WmF, W2F, qsum, cnt);
    k_fused<<<dim3(NCH, Bsz), dim3(512), 0, stream>>>(
        memory, awc, mask, WmF, W2F, Wv, bv, qsum, energ, ctxc, ml,
        cnt, ctx, wout);
}

// Round 6
// 242.265 us; speedup vs baseline: 1.6028x; 1.6028x over previous
//
#include <hip/hip_runtime.h>
#include <math.h>

#define Bsz 64
#define Tn 1000
#define QD 1024
#define MD 512
#define AD 128
#define NF 32
#define KS 31
#define PADc 15

#define NCH 16     // t-chunks
#define RPC 64     // rows per chunk
#define SUB 16     // rows per MFMA subtile
#define ROWSH 520  // shorts per LDS row (512 data + 8 pad) = 1040 B

typedef __attribute__((ext_vector_type(8))) short bf16x8;
typedef __attribute__((ext_vector_type(4))) float f32x4;

// d_ws layout (bytes)
#define OFF_ENERG 32768
#define OFF_WMF  288768
#define OFF_W2F  419840
#define OFF_ML   428032
#define OFF_CTXC 436224

static __device__ __forceinline__ short f2bf(float x) {
    unsigned u = __float_as_uint(x);
    unsigned r = (u + 0x7fffu + ((u >> 16) & 1u)) >> 16;  // RNE
    return (short)r;
}
static __device__ __forceinline__ float bf2f(short s) {
    return __uint_as_float(((unsigned)(unsigned short)s) << 16);
}
static __device__ __forceinline__ float fast_tanh(float x) {
    float e2 = __expf(2.f * x);
    return 1.f - 2.f / (e2 + 1.f);
}

// ---------------------------------------------------------------------------
// Kernel A (prep, 97 blocks x 256): WmF fragment-major bf16; qsum; W2F.
// ---------------------------------------------------------------------------
__global__ __launch_bounds__(256)
void k_prep(const float* __restrict__ Wm, const float* __restrict__ conv_w,
            const float* __restrict__ conv_b, const float* __restrict__ Wloc,
            const float* __restrict__ query, const float* __restrict__ Wq,
            const float* __restrict__ bq, const float* __restrict__ bm,
            short* __restrict__ WmF, short* __restrict__ W2F,
            float* __restrict__ qsum) {
    __shared__ float qs[QD];
    __shared__ float red[256];
    int bid = blockIdx.x;
    if (bid < 32) {
        int g = bid * 256 + threadIdx.x;
        int wc = g >> 6, l = g & 63;
        int a = (wc >> 4) * 16 + (l & 15);
        int kb = (wc & 15) * 32 + (l >> 4) * 8;
        const float* src = Wm + a * MD + kb;
        float4 v0 = *(const float4*)src;
        float4 v1 = *(const float4*)(src + 4);
        bf16x8 o;
        o[0] = f2bf(v0.x); o[1] = f2bf(v0.y); o[2] = f2bf(v0.z); o[3] = f2bf(v0.w);
        o[4] = f2bf(v1.x); o[5] = f2bf(v1.y); o[6] = f2bf(v1.z); o[7] = f2bf(v1.w);
        *(bf16x8*)(WmF + (size_t)g * 8) = o;
    } else if (bid < 96) {
        int b = bid - 32;
        int a = threadIdx.x & 127;
        int half_ = threadIdx.x >> 7;
        for (int i = threadIdx.x; i < QD; i += 256) qs[i] = query[b * QD + i];
        __syncthreads();
        const float4* Wq4 = (const float4*)(Wq + a * QD + half_ * (QD / 2));
        const float4* qs4 = (const float4*)(qs + half_ * (QD / 2));
        float acc = 0.f;
#pragma unroll 4
        for (int i = 0; i < QD / 8; ++i) {
            float4 w = Wq4[i];
            float4 q = qs4[i];
            acc += w.x * q.x + w.y * q.y + w.z * q.z + w.w * q.w;
        }
        red[threadIdx.x] = acc;
        __syncthreads();
        if (half_ == 0) {
            float b2 = 0.f;
            for (int f = 0; f < NF; ++f) b2 += conv_b[f] * Wloc[a * NF + f];
            qsum[b * AD + a] = red[a] + red[a + 128] + bq[a] + bm[a] + b2;
        }
    } else {
        for (int s = threadIdx.x * 2; s < threadIdx.x * 2 + 2; ++s) {
            int w = s >> 6, l = s & 63;
            int a = w * 16 + (l & 15);
            int kb = (l >> 4) * 8;
            bf16x8 o;
#pragma unroll
            for (int j = 0; j < 8; ++j) {
                int k = kb + j;
                float sum = 0.f;
                if (k < KS)
                    for (int f = 0; f < NF; ++f) sum += conv_w[f * KS + k] * Wloc[a * NF + f];
                o[j] = f2bf(sum);  // k>=KS columns are ZERO -> no A-side guard needed
            }
            *(bf16x8*)(W2F + s * 8) = o;
        }
    }
}

// ---------------------------------------------------------------------------
// Kernel B: fused energies + softmax + context, BARRIER-DIET edition.
//   R4 structure (depth-2 reg staging, 8 waves, 66.5 KB chunk), but only ONE
//   barrier per phase: the per-phase cross-wave reduce is deferred by writing
//   wave-partials into phase-indexed ered[4][8][.] (no cross-phase hazard),
//   and the entire 8-wave fold + energ store + masking + softmax prep is
//   batched into a single post-loop section. 11 -> 7 full-drain barriers,
//   and no single-wave serial section inside the loop.
//   NOTE: NO device-scope fences anywhere (R5 lesson: agent fences on
//   multi-XCD gfx950 write back / invalidate per-XCD L2 -> 3x regression).
// ---------------------------------------------------------------------------
__global__ __launch_bounds__(512, 4)
void k_fused(const float* __restrict__ mem, const float* __restrict__ awc,
             const unsigned char* __restrict__ mask,
             const short* __restrict__ WmF, const short* __restrict__ W2F,
             const float* __restrict__ Wv, const float* __restrict__ bv,
             const float* __restrict__ qsum, float* __restrict__ energ,
             float* __restrict__ ctxc, float2* __restrict__ ml) {
    __shared__ __align__(16) short chunk[RPC * ROWSH];  // 66560 B
    __shared__ float ered[4][8][SUB + 1];               // phase-indexed partials
    __shared__ __align__(16) float Esub[RPC];           // masked energies
    __shared__ float ps[RPC];
    __shared__ float vmask[RPC];
    __shared__ short awcsB[96];

    const int b = blockIdx.y, c = blockIdx.x;
    const int t0 = c * RPC;
    const int tid = threadIdx.x;
    const int w = tid >> 6, lane = tid & 63, m16 = lane & 15, q = lane >> 4;

    // --- prologue: issue subtile 0 AND subtile 1 loads (depth-2 prime) ---
    const float* gbase = mem + (size_t)b * Tn * MD + lane * 8;
    float4 stg[2][2][2];
#pragma unroll
    for (int s = 0; s < 2; ++s) {
#pragma unroll
        for (int rr = 0; rr < 2; ++rr) {
            int t = t0 + s * SUB + w * 2 + rr;
            int tc = t < Tn ? t : Tn - 1;
            const float* gp = gbase + (size_t)tc * MD;
            stg[s][rr][0] = *(const float4*)gp;
            stg[s][rr][1] = *(const float4*)(gp + 4);
        }
    }

    // --- stage awc window [t0-15, t0+79] and row-validity into LDS ---
    if (tid < 96) {
        int g = t0 - PADc + tid;
        float v = (tid <= 94 && g >= 0 && g < Tn) ? awc[b * Tn + g] : 0.f;
        awcsB[tid] = f2bf(v);
    }
    if (tid < RPC) {
        int t = t0 + tid;
        bool valid = (t < Tn) && (mask[b * Tn + (t < Tn ? t : 0)] == 0);
        vmask[tid] = valid ? 1.f : 0.f;
    }

    // --- B fragments ---
    bf16x8 bfr[17];
#pragma unroll
    for (int cc = 0; cc < 16; ++cc) bfr[cc] = ((const bf16x8*)WmF)[(w * 16 + cc) * 64 + lane];
    bfr[16] = ((const bf16x8*)W2F)[w * 64 + lane];

    const int a = w * 16 + m16;
    const float wvv = Wv[a];
    const float qsv = qsum[b * AD + a];
    const float bv0 = bv[0];

    asm volatile("s_waitcnt lgkmcnt(0)" ::: "memory");
    __builtin_amdgcn_s_barrier();  // awcsB / vmask visible          (bar 1)

#pragma unroll
    for (int s = 0; s < 4; ++s) {
        const int pb = s & 1;
        // consume subtile-s registers (compiler inserts exact vmcnt wait)
#pragma unroll
        for (int rr = 0; rr < 2; ++rr) {
            int row = s * SUB + w * 2 + rr;
            float4 v0 = stg[pb][rr][0];
            float4 v1 = stg[pb][rr][1];
            bf16x8 o;
            o[0] = f2bf(v0.x); o[1] = f2bf(v0.y); o[2] = f2bf(v0.z); o[3] = f2bf(v0.w);
            o[4] = f2bf(v1.x); o[5] = f2bf(v1.y); o[6] = f2bf(v1.z); o[7] = f2bf(v1.w);
            *(bf16x8*)(&chunk[row * ROWSH] + lane * 8) = o;
        }
        // THEN issue subtile-(s+2) loads into the just-freed slot.
        if (s < 2) {
#pragma unroll
            for (int rr = 0; rr < 2; ++rr) {
                int t = t0 + (s + 2) * SUB + w * 2 + rr;
                int tc = t < Tn ? t : Tn - 1;
                const float* gp = gbase + (size_t)tc * MD;
                stg[pb][rr][0] = *(const float4*)gp;
                stg[pb][rr][1] = *(const float4*)(gp + 4);
            }
        }
        asm volatile("s_waitcnt lgkmcnt(0)" ::: "memory");  // own ds_writes done
        __builtin_amdgcn_s_barrier();  // subtile s visible           (bars 2-5)

        f32x4 acc = (f32x4){0.f, 0.f, 0.f, 0.f};
        const short* arow = &chunk[(s * SUB + m16) * ROWSH + q * 8];
#pragma unroll
        for (int cc = 0; cc < 16; ++cc) {
            bf16x8 af = *(const bf16x8*)(arow + cc * 32);
            acc = __builtin_amdgcn_mfma_f32_16x16x32_bf16(af, bfr[cc], acc, 0, 0, 0);
        }
        {   // location chunk: Toeplitz window from LDS (k=31 col zeroed in W2F)
            int tl = s * SUB + m16;
            bf16x8 af;
#pragma unroll
            for (int j = 0; j < 8; ++j) af[j] = awcsB[tl + q * 8 + j];
            acc = __builtin_amdgcn_mfma_f32_16x16x32_bf16(af, bfr[16], acc, 0, 0, 0);
        }

        // per-row energy partials: tanh, dot Wv, reduce over 16 a-lanes.
        // Phase-indexed ered -> no barrier needed until after the loop.
#pragma unroll
        for (int r = 0; r < 4; ++r) {
            float e = wvv * fast_tanh(acc[r] + qsv);
#pragma unroll
            for (int m2 = 1; m2 < 16; m2 <<= 1) e += __shfl_xor(e, m2, 64);
            if (m16 == 0) ered[s][w][q * 4 + r] = e;
        }
    }

    asm volatile("s_waitcnt lgkmcnt(0)" ::: "memory");
    __builtin_amdgcn_s_barrier();  // all ered visible                (bar 6)

    // --- batched 8-wave fold + energ store + masking (wave 0 only) ---
    if (tid < RPC) {
        int sI = tid >> 4, r16 = tid & 15;
        float E = bv0;
#pragma unroll
        for (int ww = 0; ww < 8; ++ww) E += ered[sI][ww][r16];
        int t = t0 + tid;
        if (t < Tn) energ[b * Tn + t] = E;                   // raw E to global
        Esub[tid] = (vmask[tid] != 0.f) ? E : -1e30f;        // masked
    }
    asm volatile("s_waitcnt lgkmcnt(0)" ::: "memory");
    __builtin_amdgcn_s_barrier();  // Esub visible                    (bar 7)

    // --- block softmax over the 64 resident rows (vectorized max) ---
    float mx = -1e30f;
    const float4* E4 = (const float4*)Esub;
#pragma unroll
    for (int r = 0; r < RPC / 4; ++r) {
        float4 v = E4[r];
        mx = fmaxf(mx, fmaxf(fmaxf(v.x, v.y), fmaxf(v.z, v.w)));
    }
    if (tid < RPC) ps[tid] = vmask[tid] * __expf(Esub[tid] - mx);
    asm volatile("s_waitcnt lgkmcnt(0)" ::: "memory");
    __builtin_amdgcn_s_barrier();  //                                  (bar 8)

    // --- context: thread j accumulates m-dim j from the LDS chunk ---
    float ctxj = 0.f, psum = 0.f;
#pragma unroll 8
    for (int r = 0; r < RPC; ++r) {
        float p = ps[r];
        psum += p;
        ctxj += p * bf2f(chunk[r * ROWSH + tid]);
    }
    ctxc[((size_t)c * Bsz + b) * MD + tid] = ctxj;
    if (tid == 0) ml[c * Bsz + b] = make_float2(mx, psum);
}

// ---------------------------------------------------------------------------
// Kernel C: combine partials -> ctx, and raw energies -> wout.
// ---------------------------------------------------------------------------
__global__ __launch_bounds__(512)
void k_combine(const float* __restrict__ ctxc, const float2* __restrict__ ml,
               const float* __restrict__ energ, const unsigned char* __restrict__ mask,
               float* __restrict__ ctx, float* __restrict__ wout) {
    __shared__ float sm[NCH], sl[NCH];
    int b = blockIdx.x;
    int tid = threadIdx.x;
    if (tid < NCH) {
        float2 v = ml[tid * Bsz + b];
        sm[tid] = v.x;
        sl[tid] = v.y;
    }
    __syncthreads();
    float M = -1e30f;
#pragma unroll
    for (int cc = 0; cc < NCH; ++cc) M = fmaxf(M, sm[cc]);
    float L = 0.f;
#pragma unroll
    for (int cc = 0; cc < NCH; ++cc) L += sl[cc] * __expf(sm[cc] - M);
    float inv = 1.f / L;

    float s = 0.f;
#pragma unroll
    for (int cc = 0; cc < NCH; ++cc)
        s += ctxc[((size_t)cc * Bsz + b) * MD + tid] * __expf(sm[cc] - M);
    ctx[b * MD + tid] = s * inv;

#pragma unroll
    for (int i = 0; i < 2; ++i) {
        int t = tid + i * 512;
        if (t < Tn) {
            bool msk = mask[b * Tn + t] != 0;
            float e = energ[b * Tn + t];
            wout[b * Tn + t] = msk ? 0.f : __expf(e - M) * inv;
        }
    }
}

// ---------------------------------------------------------------------------
extern "C" void kernel_launch(void* const* d_in, const int* in_sizes, int n_in,
                              void* d_out, int out_size, void* d_ws, size_t ws_size,
                              hipStream_t stream) {
    const float* query  = (const float*)d_in[0];
    const float* memory = (const float*)d_in[1];
    const float* awc    = (const float*)d_in[2];
    const unsigned char* mask = (const unsigned char*)d_in[3];
    const float* Wq     = (const float*)d_in[4];
    const float* bq     = (const float*)d_in[5];
    const float* Wm     = (const float*)d_in[6];
    const float* bm     = (const float*)d_in[7];
    const float* Wv     = (const float*)d_in[8];
    const float* bv     = (const float*)d_in[9];
    const float* conv_w = (const float*)d_in[10];
    const float* conv_b = (const float*)d_in[11];
    const float* Wloc   = (const float*)d_in[12];

    float* out = (float*)d_out;
    float* ctx = out;             // [64,512]
    float* wout = out + Bsz * MD; // [64,1000]

    float* qsum  = (float*)d_ws;
    float* energ = (float*)((char*)d_ws + OFF_ENERG);
    short* WmF   = (short*)((char*)d_ws + OFF_WMF);
    short* W2F   = (short*)((char*)d_ws + OFF_W2F);
    float2* ml   = (float2*)((char*)d_ws + OFF_ML);
    float* ctxc  = (float*)((char*)d_ws + OFF_CTXC);

    k_prep<<<dim3(97), dim3(256), 0, stream>>>(Wm, conv_w, conv_b, Wloc, query, Wq,
                                               bq, bm, WmF, W2F, qsum);
    k_fused<<<dim3(NCH, Bsz), dim3(512), 0, stream>>>(
        memory, awc, mask, WmF, W2F, Wv, bv, qsum, energ, ctxc, ml);
    k_combine<<<dim3(Bsz), dim3(512), 0, stream>>>(ctxc, ml, energ, mask, ctx, wout);
}

// Round 7
// 242.183 us; speedup vs baseline: 1.6034x; 1.0003x over previous
//
#include <hip/hip_runtime.h>
#include <math.h>

#define Bsz 64
#define Tn 1000
#define QD 1024
#define MD 512
#define AD 128
#define NF 32
#define KS 31
#define PADc 15

#define NCH 16     // t-chunks
#define RPC 64     // rows per chunk
#define SUB 16     // rows per MFMA subtile
#define ROWSH 520  // shorts per LDS row (512 data + 8 pad) = 1040 B

typedef __attribute__((ext_vector_type(8))) short bf16x8;
typedef __attribute__((ext_vector_type(4))) float f32x4;

// d_ws layout (bytes)
#define OFF_ENERG 32768
#define OFF_WMF  288768
#define OFF_W2F  419840
#define OFF_ML   428032
#define OFF_CTXC 436224

static __device__ __forceinline__ short f2bf(float x) {
    unsigned u = __float_as_uint(x);
    unsigned r = (u + 0x7fffu + ((u >> 16) & 1u)) >> 16;  // RNE
    return (short)r;
}
static __device__ __forceinline__ float bf2f(short s) {
    return __uint_as_float(((unsigned)(unsigned short)s) << 16);
}
static __device__ __forceinline__ float fast_tanh(float x) {
    float e2 = __expf(2.f * x);
    return 1.f - 2.f / (e2 + 1.f);
}

// ---------------------------------------------------------------------------
// Kernel A (prep, 97 blocks x 256): WmF fragment-major bf16; qsum; W2F.
// ---------------------------------------------------------------------------
__global__ __launch_bounds__(256)
void k_prep(const float* __restrict__ Wm, const float* __restrict__ conv_w,
            const float* __restrict__ conv_b, const float* __restrict__ Wloc,
            const float* __restrict__ query, const float* __restrict__ Wq,
            const float* __restrict__ bq, const float* __restrict__ bm,
            short* __restrict__ WmF, short* __restrict__ W2F,
            float* __restrict__ qsum) {
    __shared__ float qs[QD];
    __shared__ float red[256];
    int bid = blockIdx.x;
    if (bid < 32) {
        int g = bid * 256 + threadIdx.x;
        int wc = g >> 6, l = g & 63;
        int a = (wc >> 4) * 16 + (l & 15);
        int kb = (wc & 15) * 32 + (l >> 4) * 8;
        const float* src = Wm + a * MD + kb;
        float4 v0 = *(const float4*)src;
        float4 v1 = *(const float4*)(src + 4);
        bf16x8 o;
        o[0] = f2bf(v0.x); o[1] = f2bf(v0.y); o[2] = f2bf(v0.z); o[3] = f2bf(v0.w);
        o[4] = f2bf(v1.x); o[5] = f2bf(v1.y); o[6] = f2bf(v1.z); o[7] = f2bf(v1.w);
        *(bf16x8*)(WmF + (size_t)g * 8) = o;
    } else if (bid < 96) {
        int b = bid - 32;
        int a = threadIdx.x & 127;
        int half_ = threadIdx.x >> 7;
        for (int i = threadIdx.x; i < QD; i += 256) qs[i] = query[b * QD + i];
        __syncthreads();
        const float4* Wq4 = (const float4*)(Wq + a * QD + half_ * (QD / 2));
        const float4* qs4 = (const float4*)(qs + half_ * (QD / 2));
        float acc = 0.f;
#pragma unroll 4
        for (int i = 0; i < QD / 8; ++i) {
            float4 w = Wq4[i];
            float4 q = qs4[i];
            acc += w.x * q.x + w.y * q.y + w.z * q.z + w.w * q.w;
        }
        red[threadIdx.x] = acc;
        __syncthreads();
        if (half_ == 0) {
            float b2 = 0.f;
            for (int f = 0; f < NF; ++f) b2 += conv_b[f] * Wloc[a * NF + f];
            qsum[b * AD + a] = red[a] + red[a + 128] + bq[a] + bm[a] + b2;
        }
    } else {
        for (int s = threadIdx.x * 2; s < threadIdx.x * 2 + 2; ++s) {
            int w = s >> 6, l = s & 63;
            int a = w * 16 + (l & 15);
            int kb = (l >> 4) * 8;
            bf16x8 o;
#pragma unroll
            for (int j = 0; j < 8; ++j) {
                int k = kb + j;
                float sum = 0.f;
                if (k < KS)
                    for (int f = 0; f < NF; ++f) sum += conv_w[f * KS + k] * Wloc[a * NF + f];
                o[j] = f2bf(sum);  // k>=KS columns are ZERO -> no A-side guard needed
            }
            *(bf16x8*)(W2F + s * 8) = o;
        }
    }
}

// ---------------------------------------------------------------------------
// Kernel B: fused energies + softmax + context, REGISTER-DIET edition.
//   R6 barrier-diet structure unchanged, but per-wave register footprint cut
//   below the 128-reg unified boundary (4 waves/SIMD -> 2 resident blocks/CU):
//   (1) staging single-buffered: stg[2][2] (8 VGPR, was 16) with
//       consume-then-issue into the SAME buffer (schedule-identical: consume
//       precedes re-issue in program order; loads fly across the MFMA phase);
//   (2) #pragma unroll 1 on the phase loop (kills cross-phase live-range
//       inflation from the 4x unroll).
//   Theory: bfr[17]=68 + stg16 + misc put us a few regs over 128 -> only
//   ONE 8-wave block resident/CU (3 waves/SIMD), explaining why all schedule
//   micro-opts were null. NO device-scope fences (R5 lesson).
// ---------------------------------------------------------------------------
__global__ __launch_bounds__(512, 4)
void k_fused(const float* __restrict__ mem, const float* __restrict__ awc,
             const unsigned char* __restrict__ mask,
             const short* __restrict__ WmF, const short* __restrict__ W2F,
             const float* __restrict__ Wv, const float* __restrict__ bv,
             const float* __restrict__ qsum, float* __restrict__ energ,
             float* __restrict__ ctxc, float2* __restrict__ ml) {
    __shared__ __align__(16) short chunk[RPC * ROWSH];  // 66560 B
    __shared__ float ered[4][8][SUB + 1];               // phase-indexed partials
    __shared__ __align__(16) float Esub[RPC];           // masked energies
    __shared__ float ps[RPC];
    __shared__ float vmask[RPC];
    __shared__ short awcsB[96];

    const int b = blockIdx.y, c = blockIdx.x;
    const int t0 = c * RPC;
    const int tid = threadIdx.x;
    const int w = tid >> 6, lane = tid & 63, m16 = lane & 15, q = lane >> 4;

    // --- prologue: issue subtile-0 loads (single-buffer staging) ---
    const float* gbase = mem + (size_t)b * Tn * MD + lane * 8;
    float4 stg[2][2];
#pragma unroll
    for (int rr = 0; rr < 2; ++rr) {
        int t = t0 + w * 2 + rr;
        int tc = t < Tn ? t : Tn - 1;
        const float* gp = gbase + (size_t)tc * MD;
        stg[rr][0] = *(const float4*)gp;
        stg[rr][1] = *(const float4*)(gp + 4);
    }

    // --- stage awc window [t0-15, t0+79] and row-validity into LDS ---
    if (tid < 96) {
        int g = t0 - PADc + tid;
        float v = (tid <= 94 && g >= 0 && g < Tn) ? awc[b * Tn + g] : 0.f;
        awcsB[tid] = f2bf(v);
    }
    if (tid < RPC) {
        int t = t0 + tid;
        bool valid = (t < Tn) && (mask[b * Tn + (t < Tn ? t : 0)] == 0);
        vmask[tid] = valid ? 1.f : 0.f;
    }

    // --- B fragments ---
    bf16x8 bfr[17];
#pragma unroll
    for (int cc = 0; cc < 16; ++cc) bfr[cc] = ((const bf16x8*)WmF)[(w * 16 + cc) * 64 + lane];
    bfr[16] = ((const bf16x8*)W2F)[w * 64 + lane];

    const int a = w * 16 + m16;
    const float wvv = Wv[a];
    const float qsv = qsum[b * AD + a];
    const float bv0 = bv[0];

    asm volatile("s_waitcnt lgkmcnt(0)" ::: "memory");
    __builtin_amdgcn_s_barrier();  // awcsB / vmask visible          (bar 1)

#pragma unroll 1
    for (int s = 0; s < 4; ++s) {
        // consume subtile-s registers (compiler inserts exact vmcnt wait)
#pragma unroll
        for (int rr = 0; rr < 2; ++rr) {
            int row = s * SUB + w * 2 + rr;
            float4 v0 = stg[rr][0];
            float4 v1 = stg[rr][1];
            bf16x8 o;
            o[0] = f2bf(v0.x); o[1] = f2bf(v0.y); o[2] = f2bf(v0.z); o[3] = f2bf(v0.w);
            o[4] = f2bf(v1.x); o[5] = f2bf(v1.y); o[6] = f2bf(v1.z); o[7] = f2bf(v1.w);
            *(bf16x8*)(&chunk[row * ROWSH] + lane * 8) = o;
        }
        // THEN issue subtile-(s+1) loads into the just-freed buffer; they
        // stay in flight across this phase's MFMA/reduce.
        if (s < 3) {
#pragma unroll
            for (int rr = 0; rr < 2; ++rr) {
                int t = t0 + (s + 1) * SUB + w * 2 + rr;
                int tc = t < Tn ? t : Tn - 1;
                const float* gp = gbase + (size_t)tc * MD;
                stg[rr][0] = *(const float4*)gp;
                stg[rr][1] = *(const float4*)(gp + 4);
            }
        }
        asm volatile("s_waitcnt lgkmcnt(0)" ::: "memory");  // own ds_writes done
        __builtin_amdgcn_s_barrier();  // subtile s visible           (bars 2-5)

        f32x4 acc = (f32x4){0.f, 0.f, 0.f, 0.f};
        const short* arow = &chunk[(s * SUB + m16) * ROWSH + q * 8];
#pragma unroll
        for (int cc = 0; cc < 16; ++cc) {
            bf16x8 af = *(const bf16x8*)(arow + cc * 32);
            acc = __builtin_amdgcn_mfma_f32_16x16x32_bf16(af, bfr[cc], acc, 0, 0, 0);
        }
        {   // location chunk: Toeplitz window from LDS (k=31 col zeroed in W2F)
            int tl = s * SUB + m16;
            bf16x8 af;
#pragma unroll
            for (int j = 0; j < 8; ++j) af[j] = awcsB[tl + q * 8 + j];
            acc = __builtin_amdgcn_mfma_f32_16x16x32_bf16(af, bfr[16], acc, 0, 0, 0);
        }

        // per-row energy partials: tanh, dot Wv, reduce over 16 a-lanes.
        // Phase-indexed ered -> no barrier needed until after the loop.
#pragma unroll
        for (int r = 0; r < 4; ++r) {
            float e = wvv * fast_tanh(acc[r] + qsv);
#pragma unroll
            for (int m2 = 1; m2 < 16; m2 <<= 1) e += __shfl_xor(e, m2, 64);
            if (m16 == 0) ered[s][w][q * 4 + r] = e;
        }
    }

    asm volatile("s_waitcnt lgkmcnt(0)" ::: "memory");
    __builtin_amdgcn_s_barrier();  // all ered visible                (bar 6)

    // --- batched 8-wave fold + energ store + masking ---
    if (tid < RPC) {
        int sI = tid >> 4, r16 = tid & 15;
        float E = bv0;
#pragma unroll
        for (int ww = 0; ww < 8; ++ww) E += ered[sI][ww][r16];
        int t = t0 + tid;
        if (t < Tn) energ[b * Tn + t] = E;                   // raw E to global
        Esub[tid] = (vmask[tid] != 0.f) ? E : -1e30f;        // masked
    }
    asm volatile("s_waitcnt lgkmcnt(0)" ::: "memory");
    __builtin_amdgcn_s_barrier();  // Esub visible                    (bar 7)

    // --- block softmax over the 64 resident rows (vectorized max) ---
    float mx = -1e30f;
    const float4* E4 = (const float4*)Esub;
#pragma unroll
    for (int r = 0; r < RPC / 4; ++r) {
        float4 v = E4[r];
        mx = fmaxf(mx, fmaxf(fmaxf(v.x, v.y), fmaxf(v.z, v.w)));
    }
    if (tid < RPC) ps[tid] = vmask[tid] * __expf(Esub[tid] - mx);
    asm volatile("s_waitcnt lgkmcnt(0)" ::: "memory");
    __builtin_amdgcn_s_barrier();  //                                  (bar 8)

    // --- context: thread j accumulates m-dim j from the LDS chunk ---
    float ctxj = 0.f, psum = 0.f;
#pragma unroll 8
    for (int r = 0; r < RPC; ++r) {
        float p = ps[r];
        psum += p;
        ctxj += p * bf2f(chunk[r * ROWSH + tid]);
    }
    ctxc[((size_t)c * Bsz + b) * MD + tid] = ctxj;
    if (tid == 0) ml[c * Bsz + b] = make_float2(mx, psum);
}

// ---------------------------------------------------------------------------
// Kernel C: combine partials -> ctx, and raw energies -> wout.
// ---------------------------------------------------------------------------
__global__ __launch_bounds__(512)
void k_combine(const float* __restrict__ ctxc, const float2* __restrict__ ml,
               const float* __restrict__ energ, const unsigned char* __restrict__ mask,
               float* __restrict__ ctx, float* __restrict__ wout) {
    __shared__ float sm[NCH], sl[NCH];
    int b = blockIdx.x;
    int tid = threadIdx.x;
    if (tid < NCH) {
        float2 v = ml[tid * Bsz + b];
        sm[tid] = v.x;
        sl[tid] = v.y;
    }
    __syncthreads();
    float M = -1e30f;
#pragma unroll
    for (int cc = 0; cc < NCH; ++cc) M = fmaxf(M, sm[cc]);
    float L = 0.f;
#pragma unroll
    for (int cc = 0; cc < NCH; ++cc) L += sl[cc] * __expf(sm[cc] - M);
    float inv = 1.f / L;

    float s = 0.f;
#pragma unroll
    for (int cc = 0; cc < NCH; ++cc)
        s += ctxc[((size_t)cc * Bsz + b) * MD + tid] * __expf(sm[cc] - M);
    ctx[b * MD + tid] = s * inv;

#pragma unroll
    for (int i = 0; i < 2; ++i) {
        int t = tid + i * 512;
        if (t < Tn) {
            bool msk = mask[b * Tn + t] != 0;
            float e = energ[b * Tn + t];
            wout[b * Tn + t] = msk ? 0.f : __expf(e - M) * inv;
        }
    }
}

// ---------------------------------------------------------------------------
extern "C" void kernel_launch(void* const* d_in, const int* in_sizes, int n_in,
                              void* d_out, int out_size, void* d_ws, size_t ws_size,
                              hipStream_t stream) {
    const float* query  = (const float*)d_in[0];
    const float* memory = (const float*)d_in[1];
    const float* awc    = (const float*)d_in[2];
    const unsigned char* mask = (const unsigned char*)d_in[3];
    const float* Wq     = (const float*)d_in[4];
    const float* bq     = (const float*)d_in[5];
    const float* Wm     = (const float*)d_in[6];
    const float* bm     = (const float*)d_in[7];
    const float* Wv     = (const float*)d_in[8];
    const float* bv     = (const float*)d_in[9];
    const float* conv_w = (const float*)d_in[10];
    const float* conv_b = (const float*)d_in[11];
    const float* Wloc   = (const float*)d_in[12];

    float* out = (float*)d_out;
    float* ctx = out;             // [64,512]
    float* wout = out + Bsz * MD; // [64,1000]

    float* qsum  = (float*)d_ws;
    float* energ = (float*)((char*)d_ws + OFF_ENERG);
    short* WmF   = (short*)((char*)d_ws + OFF_WMF);
    short* W2F   = (short*)((char*)d_ws + OFF_W2F);
    float2* ml   = (float2*)((char*)d_ws + OFF_ML);
    float* ctxc  = (float*)((char*)d_ws + OFF_CTXC);

    k_prep<<<dim3(97), dim3(256), 0, stream>>>(Wm, conv_w, conv_b, Wloc, query, Wq,
                                               bq, bm, WmF, W2F, qsum);
    k_fused<<<dim3(NCH, Bsz), dim3(512), 0, stream>>>(
        memory, awc, mask, WmF, W2F, Wv, bv, qsum, energ, ctxc, ml);
    k_combine<<<dim3(Bsz), dim3(512), 0, stream>>>(ctxc, ml, energ, mask, ctx, wout);
}